// Round 10
// baseline (92.553 us; speedup 1.0000x reference)
//
#include <hip/hip_runtime.h>
#include <math.h>

#define IMG_H 512
#define IMG_W 512
#define PLANE (IMG_H * IMG_W)
#define NB 9
#define LSTR 260   // interior cols at 0..255 (aligned b128), halos at 256/257

// ---- shared staging: gray band (10 rows x 258 cols) into LDS ----
__device__ __forceinline__ void stage_band(const float* __restrict__ xn,
                                           int wstart, int h0, int t,
                                           float* __restrict__ sgray) {
    if (t < 20) {   // halo cols for 10 rows: LDS idx 256 (left), 257 (right)
        const int r    = t >> 1;
        const int side = t & 1;
        const int h    = h0 - 1 + r;
        const int col  = wstart - 1 + side * 257;
        float g = 0.0f;
        if ((unsigned)h < IMG_H && (unsigned)col < IMG_W) {
            const float* p = xn + (size_t)h * IMG_W + col;
            g = ((p[0] + p[PLANE]) + p[2 * PLANE]) / 3.0f;
        }
        sgray[r * LSTR + 256 + side] = g;
    }
#pragma unroll
    for (int k = 0; k < 3; k++) {   // 10 rows x 64 float4, aligned ds_write_b128
        const int i4 = t + k * 256;
        if (i4 < 640) {
            const int r  = i4 >> 6;
            const int c4 = i4 & 63;
            const int h  = h0 - 1 + r;
            float4 gv = make_float4(0.0f, 0.0f, 0.0f, 0.0f);
            if ((unsigned)h < IMG_H) {
                const float* p = xn + (size_t)h * IMG_W + wstart + 4 * c4;
                const float4 a = *(const float4*)(p);
                const float4 b = *(const float4*)(p + PLANE);
                const float4 c = *(const float4*)(p + 2 * PLANE);
                gv.x = ((a.x + b.x) + c.x) / 3.0f;
                gv.y = ((a.y + b.y) + c.y) / 3.0f;
                gv.z = ((a.z + b.z) + c.z) / 3.0f;
                gv.w = ((a.w + b.w) + c.w) / 3.0f;
            }
            *(float4*)&sgray[r * LSTR + 4 * c4] = gv;
        }
    }
}

// ---- shared classifier (bit-exact decision chain; see correctness model) ----
__device__ __forceinline__ void classify(const float* RA, const float* RB,
                                         const float* RC,
                                         int& L, float& W0, float& W1) {
    const float tl = RA[0], tc = RA[1], tr = RA[2];
    const float ml = RB[0],             mr = RB[2];
    const float bl = RC[0], bc = RC[1], br = RC[2];
    const float gx = ((((tl - tr) + 2.0f * ml) - 2.0f * mr) + bl) - br;
    const float gy = ((((tl + 2.0f * tc) + tr) - bl) - 2.0f * bc) - br;
    const float nrm = sqrtf(gx * gx + gy * gy);
    const float fa = fabsf(gx), fb = fabsf(gy);
    const float mn = fminf(fa, fb), mx = fmaxf(fa, fb);
    float rcpmx;
    asm("v_rcp_f32 %0, %1" : "=v"(rcpmx) : "v"(mx));
    const float tt = mn * rcpmx;            // mx==0 -> NaN -> slow path
    const float ss = tt * tt;
    float po = fmaf(ss, -0.03357890f, 0.15084052f);
    po = fmaf(ss, po, -0.33355581f);
    po = fmaf(ss, po, 0.55446223f);
    po = fmaf(ss, po, -0.95289958f);
    po = fmaf(ss, po, 2.86472384f);         // poly pre-scaled by 9/pi
    float u = tt * po;
    if (fa > fb)    u = 4.5f - u;
    if (gy < 0.0f)  u = 9.0f - u;
    if (gx < 0.0f)  u = -u;
    const float fl   = floorf(u);
    const float frac = u - fl;
    const float dist = fminf(frac, 1.0f - frac);
    if (dist > 2.5e-4f) {                   // NaN -> false -> slow
        int lo = (int)fl; if (lo < 0) lo += NB;
        L = lo; W0 = nrm; W1 = 1.0f - nrm;
    } else {
        // exact reference chain (bit-identical to rounds 2-9)
        const float ph  = (float)atan2((double)gx, (double)gy);
        const float pbf = ph / (float)M_PI * 9.0f;
        int lo = (int)floorf(pbf) % NB; if (lo < 0) lo += NB;
        int hi = (int)ceilf(pbf)  % NB; if (hi < 0) hi += NB;
        L = lo;
        if (lo == hi) { W0 = nrm + (1.0f - nrm); W1 = 0.0f; }
        else          { W0 = nrm; W1 = 1.0f - nrm; }
    }
}

// ---- DIAG 1: staging only ----
__global__ __launch_bounds__(256, 8) void diag_stage(const float* __restrict__ x,
                                                     float* __restrict__ ws) {
    __shared__ float sgray[10 * LSTR];
    const int t    = threadIdx.x;
    const int n    = blockIdx.x >> 7;
    const int r7   = blockIdx.x & 127;
    stage_band(x + (size_t)n * 3 * PLANE, (r7 & 1) * 256, (r7 >> 1) * 8, t, sgray);
    __syncthreads();
    float s = 0.0f;
#pragma unroll
    for (int r = 0; r < 10; r++) s += sgray[r * LSTR + t];   // consume LDS
    if (t < 20) s += sgray[(t >> 1) * LSTR + 256 + (t & 1)];
    ws[(size_t)blockIdx.x * 256 + t] = s;
}

// ---- DIAG 2: staging + sobel + norm + classifier (no bin scatter/reduce) ----
__global__ __launch_bounds__(256, 8) void diag_noscatter(const float* __restrict__ x,
                                                         float* __restrict__ ws) {
    __shared__ float sgray[10 * LSTR];
    const int t    = threadIdx.x;
    const int n    = blockIdx.x >> 7;
    const int r7   = blockIdx.x & 127;
    stage_band(x + (size_t)n * 3 * PLANE, (r7 & 1) * 256, (r7 >> 1) * 8, t, sgray);
    __syncthreads();

    const int aL = (t == 0)   ? 256 : (t - 1);
    const int aR = (t == 255) ? 257 : (t + 1);
    float raA[3], rbA[3], rcA[3], raB[3], rbB[3], rcB[3];
    {
        const float* r0 = &sgray[0 * LSTR];
        const float* r1 = &sgray[1 * LSTR];
        const float* r4 = &sgray[4 * LSTR];
        const float* r5 = &sgray[5 * LSTR];
        raA[0] = r0[aL]; raA[1] = r0[t]; raA[2] = r0[aR];
        rbA[0] = r1[aL]; rbA[1] = r1[t]; rbA[2] = r1[aR];
        raB[0] = r4[aL]; raB[1] = r4[t]; raB[2] = r4[aR];
        rbB[0] = r5[aL]; rbB[1] = r5[t]; rbB[2] = r5[aR];
    }
    float acc = 0.0f;
#pragma unroll
    for (int k = 0; k < 4; k++) {
        const float* rA = &sgray[(k + 2) * LSTR];
        const float* rB = &sgray[(k + 6) * LSTR];
        rcA[0] = rA[aL]; rcA[1] = rA[t]; rcA[2] = rA[aR];
        rcB[0] = rB[aL]; rcB[1] = rB[t]; rcB[2] = rB[aR];
        int lA, lB; float w0A, w1A, w0B, w1B;
        classify(raA, rbA, rcA, lA, w0A, w1A);
        classify(raB, rbB, rcB, lB, w0B, w1B);
        acc += w0A * (float)(lA + 1) + w1A;      // keep l/w0/w1 all live
        acc += w0B * (float)(lB + 1) + w1B;
#pragma unroll
        for (int q = 0; q < 3; q++) {
            raA[q] = rbA[q]; rbA[q] = rcA[q];
            raB[q] = rbB[q]; rbB[q] = rcB[q];
        }
    }
    ws[(size_t)blockIdx.x * 256 + t] = acc;
}

// ---- FULL kernel (r8, unchanged; produces d_out) ----
__global__ __launch_bounds__(256, 8) void hog_kernel(const float* __restrict__ x,
                                                     float* __restrict__ out) {
    __shared__ float sgray[10 * LSTR];
    const int t    = threadIdx.x;
    const int n    = blockIdx.x >> 7;
    const int r7   = blockIdx.x & 127;
    const int cy   = r7 >> 1;
    const int half = r7 & 1;
    stage_band(x + (size_t)n * 3 * PLANE, half * 256, cy * 8, t, sgray);
    __syncthreads();

    const int aL = (t == 0)   ? 256 : (t - 1);
    const int aR = (t == 255) ? 257 : (t + 1);
    float bins[NB];
#pragma unroll
    for (int b = 0; b < NB; b++) bins[b] = 0.0f;

    float raA[3], rbA[3], rcA[3], raB[3], rbB[3], rcB[3];
    {
        const float* r0 = &sgray[0 * LSTR];
        const float* r1 = &sgray[1 * LSTR];
        const float* r4 = &sgray[4 * LSTR];
        const float* r5 = &sgray[5 * LSTR];
        raA[0] = r0[aL]; raA[1] = r0[t]; raA[2] = r0[aR];
        rbA[0] = r1[aL]; rbA[1] = r1[t]; rbA[2] = r1[aR];
        raB[0] = r4[aL]; raB[1] = r4[t]; raB[2] = r4[aR];
        rbB[0] = r5[aL]; rbB[1] = r5[t]; rbB[2] = r5[aR];
    }

#pragma unroll
    for (int k = 0; k < 4; k++) {
        const float* rA = &sgray[(k + 2) * LSTR];
        const float* rB = &sgray[(k + 6) * LSTR];
        rcA[0] = rA[aL]; rcA[1] = rA[t]; rcA[2] = rA[aR];
        rcB[0] = rB[aL]; rcB[1] = rB[t]; rcB[2] = rB[aR];

        int lA, lB; float w0A, w1A, w0B, w1B;
        classify(raA, rbA, rcA, lA, w0A, w1A);
        classify(raB, rbB, rcB, lB, w0B, w1B);

        bool mA[NB], mB[NB];
#pragma unroll
        for (int b = 0; b < NB; b++) { mA[b] = (lA == b); mB[b] = (lB == b); }
#pragma unroll
        for (int b = 0; b < NB; b++) {
            const int bp = (b + 8) % 9;
            bins[b] += (mA[b] ? w0A : (mA[bp] ? w1A : 0.0f))
                     + (mB[b] ? w0B : (mB[bp] ? w1B : 0.0f));
        }
#pragma unroll
        for (int q = 0; q < 3; q++) {
            raA[q] = rbA[q]; rbA[q] = rcA[q];
            raB[q] = rbB[q]; rbB[q] = rcB[q];
        }
    }

    __syncthreads();
    float* sred = sgray;   // alias: 2304 <= 2600 floats
#pragma unroll
    for (int b = 0; b < NB; b++) sred[t * NB + b] = bins[b];
    __syncthreads();

    for (int idx = t; idx < NB * 32; idx += 256) {
        const int b  = idx >> 5;
        const int cc = idx & 31;
        const int base = 8 * cc * NB + b;
        float s = sred[base];
#pragma unroll
        for (int j = 1; j < 8; j++) s += sred[base + j * NB];
        out[((size_t)n * NB + b) * 4096 + (size_t)cy * 64 + half * 32 + cc]
            = s * (1.0f / 64.0f);
    }
}

extern "C" void kernel_launch(void* const* d_in, const int* in_sizes, int n_in,
                              void* d_out, int out_size, void* d_ws, size_t ws_size,
                              hipStream_t stream) {
    const float* x = (const float*)d_in[0];
    float* out = (float*)d_out;
    // DIAGNOSTIC ROUND: phase-ablation kernels (results read from rocprof
    // per-dispatch rows); real kernel runs last and owns d_out.
    if (ws_size >= (size_t)4096 * 256 * 4) {
        float* ws = (float*)d_ws;
        diag_stage<<<4096, 256, 0, stream>>>(x, ws);
        diag_noscatter<<<4096, 256, 0, stream>>>(x, ws);
    }
    hog_kernel<<<4096, 256, 0, stream>>>(x, out);
}